// Round 7
// baseline (61435.010 us; speedup 1.0000x reference)
//
#include <hip/hip_runtime.h>
#include <stdint.h>
#include <stddef.h>

typedef unsigned int u32;
typedef unsigned short u16;
typedef __attribute__((ext_vector_type(4))) float f32x4;
typedef __attribute__((ext_vector_type(4))) u32 u32x4;
typedef __bf16 bf16x8 __attribute__((ext_vector_type(8)));

#define TCH 100                   // time chunk for wx
#define NCH 5
#define M_CH (128 * TCH)          // chunk rows: mm = r*TCH + tt

// ws layout (total 199,294,976 B < 212 MB proven safe):
#define OFF_WX  0ull              // f32 [128*TCH][1024]   52,428,800
#define OFF_HSA 52428800ull       // u16 [128][500][512]   65,536,000
#define OFF_HSB 117964800ull      // u16 [128][500][512]   65,536,000
#define OFF_XB  183500800ull      // u16 [64][500][128]     8,192,000
#define OFF_WT0 191692800ull      // u16 [1024][128]          262,144
#define OFF_WT1 191954944ull      // u16 [1024][1024]       2,097,152
#define OFF_WT2 194052096ull      // u16 [1024][1024]       2,097,152
#define OFF_UT0 196149248ull      // u16 [1024][512]        1,048,576
#define OFF_UT1 197197824ull
#define OFF_UT2 198246400ull

__device__ __forceinline__ float bf2f(u16 u) {
  union { u32 i; float f; } v; v.i = ((u32)u) << 16; return v.f;
}
__device__ __forceinline__ u16 f2bf(float f) {
  union { float f; u32 i; } v; v.f = f;
  u32 x = v.i;
  return (u16)((x + 0x7FFFu + ((x >> 16) & 1u)) >> 16);   // RNE
}
__device__ __forceinline__ f32x4 mfma16(bf16x8 a, bf16x8 b, f32x4 c) {
  return __builtin_amdgcn_mfma_f32_16x16x32_bf16(a, b, c, 0, 0, 0);
}
__device__ __forceinline__ bf16x8 ldfrag(const u16* p) {
  return __builtin_bit_cast(bf16x8, *(const u32x4*)p);
}

// ---------------- convert: bf16 copies (xb pad 89->128; Wt/Ut n-major) --------
#define NE_XB  4096000
#define NE_W0  131072
#define NE_W12 1048576
#define NE_UT  524288
#define N_TOTAL (NE_XB + NE_W0 + 2*NE_W12 + 3*NE_UT)

__global__ void convert_kernel(const float* __restrict__ batch,
                               const float* __restrict__ W0, const float* __restrict__ U0,
                               const float* __restrict__ W1, const float* __restrict__ U1,
                               const float* __restrict__ W2, const float* __restrict__ U2,
                               u16* __restrict__ xb, u16* __restrict__ Wt0,
                               u16* __restrict__ Wt1, u16* __restrict__ Wt2,
                               u16* __restrict__ Ut0, u16* __restrict__ Ut1,
                               u16* __restrict__ Ut2) {
  size_t idx = (size_t)blockIdx.x * 256 + threadIdx.x;
  if (idx >= N_TOTAL) return;
  size_t i = idx;
  if (i < NE_XB) {
    int d = i & 127; size_t bt = i >> 7;
    xb[i] = f2bf((d < 89) ? batch[bt * 89 + d] : 0.f);
    return;
  }
  i -= NE_XB;
  if (i < NE_W0) { int k = i & 127; int n = i >> 7;
    Wt0[i] = f2bf((k < 89) ? W0[(size_t)k * 1024 + n] : 0.f); return; }
  i -= NE_W0;
  if (i < NE_W12) { int k = i & 1023; int n = i >> 10; Wt1[i] = f2bf(W1[(size_t)k*1024 + n]); return; }
  i -= NE_W12;
  if (i < NE_W12) { int k = i & 1023; int n = i >> 10; Wt2[i] = f2bf(W2[(size_t)k*1024 + n]); return; }
  i -= NE_W12;
  if (i < NE_UT) { int k = i & 511; int g = i >> 9; Ut0[i] = f2bf(U0[(size_t)k*1024 + g]); return; }
  i -= NE_UT;
  if (i < NE_UT) { int k = i & 511; int g = i >> 9; Ut1[i] = f2bf(U1[(size_t)k*1024 + g]); return; }
  i -= NE_UT;
  { int k = i & 511; int g = i >> 9; Ut2[i] = f2bf(U2[(size_t)k*1024 + g]); }
}

// ---------------- wx GEMM (bf16 MFMA, m97 convention, f32 out) ----------------
// MODE 0: A = xb u16 [64][500][128], K=128. MODE 1: A = hs u16 [128][500][512],
// K=1024 (bidir concat gather). Bt: [1024][K] n-major. wx: [M_CH][1024] f32.
template <int MODE>
__global__ __launch_bounds__(256, 2) void wx_gemm_bf16(const u16* __restrict__ A,
                                                       const u16* __restrict__ Bt,
                                                       float* __restrict__ wx, int t0) {
  constexpr int K = (MODE == 0) ? 128 : 1024;
  __shared__ u16 Al[128 * 72];
  __shared__ u16 Bl[128 * 72];
  const int m0 = blockIdx.x * 128;
  const int n0 = blockIdx.y * 128;
  const int tid = threadIdx.x;
  const int srow = tid >> 1, so = (tid & 1) * 32;
  const int mm = m0 + srow;
  const int r = mm / TCH, tt = mm - r * TCH;
  const int t = t0 + tt;
  size_t fwd_off, bwd_off;
  if (MODE == 0) {
    fwd_off = (r < 64) ? ((size_t)r * 500 + t) * 128
                       : ((size_t)(r - 64) * 500 + (499 - t)) * 128;
    bwd_off = fwd_off;
  } else {
    int fr, ft, br, bt;
    if (r < 64) { fr = r; ft = t; br = 64 + r; bt = 499 - t; }
    else        { fr = r - 64; ft = 499 - t; br = r; bt = t; }
    fwd_off = ((size_t)fr * 500 + ft) * 512;
    bwd_off = ((size_t)br * 500 + bt) * 512;
  }
  const size_t boff0 = (size_t)(n0 + srow) * K;

  const int w = tid >> 6, l = tid & 63;
  const int wm = w & 1, wn = w >> 1;
  const int lr = l & 15, lg = l >> 4;

  f32x4 acc[4][4];
#pragma unroll
  for (int i = 0; i < 4; ++i)
#pragma unroll
    for (int j = 0; j < 4; ++j) acc[i][j] = 0.f;

  for (int k0 = 0; k0 < K; k0 += 64) {
    const size_t aoff = (MODE == 0) ? (fwd_off + k0)
                                    : ((k0 < 512) ? (fwd_off + k0) : (bwd_off + (k0 - 512)));
    {
      const u16* as = A + aoff + so;
      const u16* bs = Bt + boff0 + k0 + so;
      u16* ad = Al + srow * 72 + so;
      u16* bd = Bl + srow * 72 + so;
#pragma unroll
      for (int c = 0; c < 4; ++c) {
        *(u32x4*)(ad + c * 8) = *(const u32x4*)(as + c * 8);
        *(u32x4*)(bd + c * 8) = *(const u32x4*)(bs + c * 8);
      }
    }
    __syncthreads();
#pragma unroll
    for (int k32 = 0; k32 < 2; ++k32) {
      bf16x8 af[4], bf[4];
#pragma unroll
      for (int i = 0; i < 4; ++i)
        af[i] = ldfrag(Al + (wm * 64 + i * 16 + lr) * 72 + k32 * 32 + lg * 8);
#pragma unroll
      for (int j = 0; j < 4; ++j)
        bf[j] = ldfrag(Bl + (wn * 64 + j * 16 + lr) * 72 + k32 * 32 + lg * 8);
#pragma unroll
      for (int i = 0; i < 4; ++i)
#pragma unroll
        for (int j = 0; j < 4; ++j)
          acc[i][j] = mfma16(af[i], bf[j], acc[i][j]);
    }
    __syncthreads();
  }
#pragma unroll
  for (int i = 0; i < 4; ++i)
#pragma unroll
    for (int j = 0; j < 4; ++j)
#pragma unroll
      for (int jj = 0; jj < 4; ++jj) {
        const int row = wm * 64 + i * 16 + lg * 4 + jj;   // D: row=(lane>>4)*4+reg
        const int col = n0 + wn * 64 + j * 16 + lr;       //    col=lane&15
        wx[(size_t)(m0 + row) * 1024 + col] = acc[i][j][jj];
      }
}

// ---------------- recurrence (MFMA, communication-free, 8 blocks) -------------
// Block b owns rows r0g=b*16..+16 (all 512 h-cols -> no cross-block coupling).
// 8 waves x 4 col-tile-pairs. h in registers (D-layout) + LDS bf16 mirror for
// next step's A-frags. U fragments streamed from L2-resident bf16 Ut each step.
__global__ __launch_bounds__(512, 2) void rec_mfma(const float* __restrict__ wx,
                                                   const u16* __restrict__ Ut,
                                                   u16* __restrict__ hs_out, int t0) {
  __shared__ u16 hlds[16][520];   // pad 512->520: b128 reads hit the 8-cyc floor
  const int tid = threadIdx.x;
  const int w = tid >> 6, l = tid & 63;
  const int lr = l & 15, lg = l >> 4;
  const int r0g = blockIdx.x * 16;
  const int cb = w * 64;

  float ho[4][4];                 // [tile n][row reg jj], col = cb+n*16+lr
  if (t0 == 0) {
#pragma unroll
    for (int n = 0; n < 4; ++n)
#pragma unroll
      for (int jj = 0; jj < 4; ++jj) ho[n][jj] = 0.f;
  } else {
#pragma unroll
    for (int n = 0; n < 4; ++n)
#pragma unroll
      for (int jj = 0; jj < 4; ++jj)
        ho[n][jj] = bf2f(hs_out[((size_t)(r0g + lg * 4 + jj) * 500 + (t0 - 1)) * 512
                                + cb + n * 16 + lr]);
  }
#pragma unroll
  for (int n = 0; n < 4; ++n)
#pragma unroll
    for (int jj = 0; jj < 4; ++jj)
      hlds[lg * 4 + jj][cb + n * 16 + lr] = f2bf(ho[n][jj]);
  __syncthreads();

  for (int tt = 0; tt < TCH; ++tt) {
    const int t = t0 + tt;
    bf16x8 af[16];
#pragma unroll
    for (int kt = 0; kt < 16; ++kt)
      af[kt] = ldfrag(&hlds[lr][kt * 32 + lg * 8]);
    __syncthreads();              // all waves done reading state t-1

    f32x4 aca[4], acz[4];
#pragma unroll
    for (int n = 0; n < 4; ++n)
#pragma unroll
      for (int jj = 0; jj < 4; ++jj) {
        const float* wp = wx + ((size_t)(r0g + lg * 4 + jj) * TCH + tt) * 1024
                             + cb + n * 16 + lr;
        aca[n][jj] = wp[0];
        acz[n][jj] = wp[512];
      }
#pragma unroll 4
    for (int kt = 0; kt < 16; ++kt) {
#pragma unroll
      for (int n = 0; n < 4; ++n) {
        const size_t ua = (size_t)(cb + n * 16 + lr) * 512 + kt * 32 + lg * 8;
        aca[n] = mfma16(af[kt], ldfrag(Ut + ua), aca[n]);
        acz[n] = mfma16(af[kt], ldfrag(Ut + ua + 512 * 512), acz[n]);
      }
    }
#pragma unroll
    for (int n = 0; n < 4; ++n)
#pragma unroll
      for (int jj = 0; jj < 4; ++jj) {
        float zz = 1.f / (1.f + expf(-acz[n][jj]));
        float th = tanhf(aca[n][jj]);
        float hn = zz * ho[n][jj] + (1.f - zz) * th;
        ho[n][jj] = hn;
        u16 hb = f2bf(hn);
        hs_out[((size_t)(r0g + lg * 4 + jj) * 500 + t) * 512 + cb + n * 16 + lr] = hb;
        hlds[lg * 4 + jj][cb + n * 16 + lr] = hb;
      }
    __syncthreads();              // state t fully published in hlds
  }
}

// ---------------- final FC (fp32 compute, bf16 h input) -----------------------
__global__ __launch_bounds__(256) void fc_f32(const u16* __restrict__ hs,
                                              const float* __restrict__ Wfc,
                                              const float* __restrict__ bfc,
                                              float* __restrict__ out) {
  __shared__ float rows[16][1024];
  const int tid = threadIdx.x;
  const int pair0 = blockIdx.x * 16;
  for (int c = tid; c < 2048; c += 256) {
    int p = c >> 7, chunk = c & 127;
    int pr = pair0 + p;
    int b = pr / 500, t = pr - b * 500;
    size_t off;
    if (chunk < 64) off = ((size_t)b * 500 + t) * 512 + (size_t)chunk * 8;
    else            off = ((size_t)(64 + b) * 500 + (499 - t)) * 512 + (size_t)(chunk - 64) * 8;
    u32x4 vh = *(const u32x4*)(hs + off);
    const u16* ph = (const u16*)&vh;
    float* dst = &rows[p][chunk * 8];
#pragma unroll
    for (int e = 0; e < 8; ++e) dst[e] = bf2f(ph[e]);
  }
  __syncthreads();
#pragma unroll
  for (int rep = 0; rep < 3; ++rep) {
    int oi = rep * 256 + tid;
    if (oi < 640) {
      int p = oi / 40, o = oi - p * 40;
      float acc = bfc[o];
#pragma unroll 8
      for (int gg = 0; gg < 1024; ++gg)
        acc = fmaf(rows[p][gg], Wfc[gg * 40 + o], acc);
      out[(size_t)(pair0 + p) * 40 + o] = acc;
    }
  }
}

// ---------------- launch ------------------------------------------------------
extern "C" void kernel_launch(void* const* d_in, const int* in_sizes, int n_in,
                              void* d_out, int out_size, void* d_ws, size_t ws_size,
                              hipStream_t stream) {
  const float* batch = (const float*)d_in[0];
  const float* W0 = (const float*)d_in[2];
  const float* U0 = (const float*)d_in[3];
  const float* W1 = (const float*)d_in[4];
  const float* U1 = (const float*)d_in[5];
  const float* W2 = (const float*)d_in[6];
  const float* U2 = (const float*)d_in[7];
  const float* Wfc = (const float*)d_in[8];
  const float* bfc = (const float*)d_in[9];
  float* out = (float*)d_out;

  char* ws = (char*)d_ws;
  float* wx = (float*)(ws + OFF_WX);
  u16* hsA = (u16*)(ws + OFF_HSA);
  u16* hsB = (u16*)(ws + OFF_HSB);
  u16* xb  = (u16*)(ws + OFF_XB);
  u16* Wt0 = (u16*)(ws + OFF_WT0);
  u16* Wt1 = (u16*)(ws + OFF_WT1);
  u16* Wt2 = (u16*)(ws + OFF_WT2);
  u16* Ut0 = (u16*)(ws + OFF_UT0);
  u16* Ut1 = (u16*)(ws + OFF_UT1);
  u16* Ut2 = (u16*)(ws + OFF_UT2);

  const int cgrid = (int)((N_TOTAL + 255) / 256);
  convert_kernel<<<cgrid, 256, 0, stream>>>(batch, W0, U0, W1, U1, W2, U2,
                                            xb, Wt0, Wt1, Wt2, Ut0, Ut1, Ut2);

  dim3 ggrid(M_CH / 128, 8);
  // layer 0: reads xb, writes hsA
  for (int c = 0; c < NCH; ++c) {
    wx_gemm_bf16<0><<<ggrid, 256, 0, stream>>>(xb, Wt0, wx, c * TCH);
    rec_mfma<<<8, 512, 0, stream>>>(wx, Ut0, hsA, c * TCH);
  }
  // layer 1: reads hsA, writes hsB (ping-pong: WAR-safe)
  for (int c = 0; c < NCH; ++c) {
    wx_gemm_bf16<1><<<ggrid, 256, 0, stream>>>(hsA, Wt1, wx, c * TCH);
    rec_mfma<<<8, 512, 0, stream>>>(wx, Ut1, hsB, c * TCH);
  }
  // layer 2: reads hsB, writes hsA
  for (int c = 0; c < NCH; ++c) {
    wx_gemm_bf16<1><<<ggrid, 256, 0, stream>>>(hsB, Wt2, wx, c * TCH);
    rec_mfma<<<8, 512, 0, stream>>>(wx, Ut2, hsA, c * TCH);
  }
  fc_f32<<<2000, 256, 0, stream>>>(hsA, Wfc, bfc, out);
}

// Round 8
// 11911.375 us; speedup vs baseline: 5.1577x; 5.1577x over previous
//
#include <hip/hip_runtime.h>
#include <stdint.h>
#include <stddef.h>

typedef unsigned int u32;
typedef unsigned short u16;
typedef __attribute__((ext_vector_type(4))) float f32x4;
typedef __attribute__((ext_vector_type(4))) u32 u32x4;
typedef __bf16 bf16x8 __attribute__((ext_vector_type(8)));

#define TCH 100                   // time chunk for wx
#define NCH 5
#define M_CH (128 * TCH)          // chunk rows: mm = r*TCH + tt

// ws layout (total 199,344,128 B < 212 MB proven safe):
#define OFF_WX  0ull              // f32 [128*TCH][1024]   52,428,800
#define OFF_HSA 52428800ull       // u16 [128][500][512]   65,536,000
#define OFF_HSB 117964800ull      // u16 [128][500][512]   65,536,000
#define OFF_XB  183500800ull      // u16 [64][500][128]     8,192,000
#define OFF_WT0 191692800ull      // u16 [1024][128]          262,144
#define OFF_WT1 191954944ull      // u16 [1024][1024]       2,097,152
#define OFF_WT2 194052096ull      // u16 [1024][1024]       2,097,152
#define OFF_UT0 196149248ull      // u16 [1024][512]        1,048,576
#define OFF_UT1 197197824ull
#define OFF_UT2 198246400ull
#define OFF_CNT 199294976ull      // int [3][8][512]           49,152

__device__ __forceinline__ float bf2f(u16 u) {
  union { u32 i; float f; } v; v.i = ((u32)u) << 16; return v.f;
}
__device__ __forceinline__ u16 f2bf(float f) {
  union { float f; u32 i; } v; v.f = f;
  u32 x = v.i;
  return (u16)((x + 0x7FFFu + ((x >> 16) & 1u)) >> 16);   // RNE
}
__device__ __forceinline__ f32x4 mfma16(bf16x8 a, bf16x8 b, f32x4 c) {
  return __builtin_amdgcn_mfma_f32_16x16x32_bf16(a, b, c, 0, 0, 0);
}
__device__ __forceinline__ bf16x8 ldfrag(const u16* p) {
  return __builtin_bit_cast(bf16x8, *(const u32x4*)p);
}

// ---------------- convert: bf16 copies + zero flags ---------------------------
#define NE_XB  4096000
#define NE_W0  131072
#define NE_W12 1048576
#define NE_UT  524288
#define NE_CNT 12288
#define N_TOTAL (NE_XB + NE_W0 + 2*NE_W12 + 3*NE_UT + NE_CNT)

__global__ void convert_kernel(const float* __restrict__ batch,
                               const float* __restrict__ W0, const float* __restrict__ U0,
                               const float* __restrict__ W1, const float* __restrict__ U1,
                               const float* __restrict__ W2, const float* __restrict__ U2,
                               u16* __restrict__ xb, u16* __restrict__ Wt0,
                               u16* __restrict__ Wt1, u16* __restrict__ Wt2,
                               u16* __restrict__ Ut0, u16* __restrict__ Ut1,
                               u16* __restrict__ Ut2, int* __restrict__ cnt) {
  size_t idx = (size_t)blockIdx.x * 256 + threadIdx.x;
  if (idx >= N_TOTAL) return;
  size_t i = idx;
  if (i < NE_XB) {
    int d = i & 127; size_t bt = i >> 7;
    xb[i] = f2bf((d < 89) ? batch[bt * 89 + d] : 0.f);
    return;
  }
  i -= NE_XB;
  if (i < NE_W0) { int k = i & 127; int n = i >> 7;
    Wt0[i] = f2bf((k < 89) ? W0[(size_t)k * 1024 + n] : 0.f); return; }
  i -= NE_W0;
  if (i < NE_W12) { int k = i & 1023; int n = i >> 10; Wt1[i] = f2bf(W1[(size_t)k*1024 + n]); return; }
  i -= NE_W12;
  if (i < NE_W12) { int k = i & 1023; int n = i >> 10; Wt2[i] = f2bf(W2[(size_t)k*1024 + n]); return; }
  i -= NE_W12;
  if (i < NE_UT) { int k = i & 511; int g = i >> 9; Ut0[i] = f2bf(U0[(size_t)k*1024 + g]); return; }
  i -= NE_UT;
  if (i < NE_UT) { int k = i & 511; int g = i >> 9; Ut1[i] = f2bf(U1[(size_t)k*1024 + g]); return; }
  i -= NE_UT;
  if (i < NE_UT) { int k = i & 511; int g = i >> 9; Ut2[i] = f2bf(U2[(size_t)k*1024 + g]); return; }
  i -= NE_UT;
  cnt[i] = 0;
}

// ---------------- wx GEMM (bf16 MFMA, round-7-validated) ----------------------
template <int MODE>
__global__ __launch_bounds__(256, 2) void wx_gemm_bf16(const u16* __restrict__ A,
                                                       const u16* __restrict__ Bt,
                                                       float* __restrict__ wx, int t0) {
  constexpr int K = (MODE == 0) ? 128 : 1024;
  __shared__ u16 Al[128 * 72];
  __shared__ u16 Bl[128 * 72];
  const int m0 = blockIdx.x * 128;
  const int n0 = blockIdx.y * 128;
  const int tid = threadIdx.x;
  const int srow = tid >> 1, so = (tid & 1) * 32;
  const int mm = m0 + srow;
  const int r = mm / TCH, tt = mm - r * TCH;
  const int t = t0 + tt;
  size_t fwd_off, bwd_off;
  if (MODE == 0) {
    fwd_off = (r < 64) ? ((size_t)r * 500 + t) * 128
                       : ((size_t)(r - 64) * 500 + (499 - t)) * 128;
    bwd_off = fwd_off;
  } else {
    int fr, ft, br, bt;
    if (r < 64) { fr = r; ft = t; br = 64 + r; bt = 499 - t; }
    else        { fr = r - 64; ft = 499 - t; br = r; bt = t; }
    fwd_off = ((size_t)fr * 500 + ft) * 512;
    bwd_off = ((size_t)br * 500 + bt) * 512;
  }
  const size_t boff0 = (size_t)(n0 + srow) * K;

  const int w = tid >> 6, l = tid & 63;
  const int wm = w & 1, wn = w >> 1;
  const int lr = l & 15, lg = l >> 4;

  f32x4 acc[4][4];
#pragma unroll
  for (int i = 0; i < 4; ++i)
#pragma unroll
    for (int j = 0; j < 4; ++j) acc[i][j] = 0.f;

  for (int k0 = 0; k0 < K; k0 += 64) {
    const size_t aoff = (MODE == 0) ? (fwd_off + k0)
                                    : ((k0 < 512) ? (fwd_off + k0) : (bwd_off + (k0 - 512)));
    {
      const u16* as = A + aoff + so;
      const u16* bs = Bt + boff0 + k0 + so;
      u16* ad = Al + srow * 72 + so;
      u16* bd = Bl + srow * 72 + so;
#pragma unroll
      for (int c = 0; c < 4; ++c) {
        *(u32x4*)(ad + c * 8) = *(const u32x4*)(as + c * 8);
        *(u32x4*)(bd + c * 8) = *(const u32x4*)(bs + c * 8);
      }
    }
    __syncthreads();
#pragma unroll
    for (int k32 = 0; k32 < 2; ++k32) {
      bf16x8 af[4], bf[4];
#pragma unroll
      for (int i = 0; i < 4; ++i)
        af[i] = ldfrag(Al + (wm * 64 + i * 16 + lr) * 72 + k32 * 32 + lg * 8);
#pragma unroll
      for (int j = 0; j < 4; ++j)
        bf[j] = ldfrag(Bl + (wn * 64 + j * 16 + lr) * 72 + k32 * 32 + lg * 8);
#pragma unroll
      for (int i = 0; i < 4; ++i)
#pragma unroll
        for (int j = 0; j < 4; ++j)
          acc[i][j] = mfma16(af[i], bf[j], acc[i][j]);
    }
    __syncthreads();
  }
#pragma unroll
  for (int i = 0; i < 4; ++i)
#pragma unroll
    for (int j = 0; j < 4; ++j)
#pragma unroll
      for (int jj = 0; jj < 4; ++jj) {
        const int row = wm * 64 + i * 16 + lg * 4 + jj;   // D: row=(lane>>4)*4+reg
        const int col = n0 + wn * 64 + j * 16 + lr;       //    col=lane&15
        wx[(size_t)(m0 + row) * 1024 + col] = acc[i][j][jj];
      }
}

// ---------------- recurrence: 64-block flag-synced, U in VGPRs ----------------
// 8 row-groups (16 rows) x 8 col-groups (64 h-cols). bid&7 = rg keeps a
// row-group's 8 blocks on one XCD (perf heuristic; agent fences keep it
// correct under any placement). Flags: cnt[rg*512 + t] counts col-groups done.
__global__ __launch_bounds__(256, 1) void ligru_rec(const float* __restrict__ wx,
                                                    const u16* __restrict__ Ut,
                                                    u16* __restrict__ hs_out,
                                                    int* __restrict__ cnt, int t0) {
  const int bid = blockIdx.x;
  const int rg = bid & 7;
  const int cg = bid >> 3;
  const int tid = threadIdx.x;
  const int w = tid >> 6, l = tid & 63;
  const int lr = l & 15, lg = l >> 4;
  const int r0 = rg * 16;
  const int ca = cg * 64 + w * 16 + lr;      // owned h/a col; z col = 512+ca
  int* const cflag = cnt + rg * 512;

  // U B-fragments resident in VGPRs (zero per-step U traffic)
  bf16x8 ba[16], bz[16];
#pragma unroll
  for (int kt = 0; kt < 16; ++kt) {
    const size_t oa = (size_t)ca * 512 + kt * 32 + lg * 8;
    ba[kt] = ldfrag(Ut + oa);
    bz[kt] = ldfrag(Ut + oa + 512 * 512);
  }
  const size_t A0 = ((size_t)(r0 + lr) * 500) * 512 + lg * 8;

  float h[4];
#pragma unroll
  for (int j = 0; j < 4; ++j) {
    if (t0 == 0) h[j] = 0.f;
    else h[j] = bf2f(hs_out[((size_t)(r0 + lg * 4 + j) * 500 + (t0 - 1)) * 512 + ca]);
  }

  for (int tt = 0; tt < TCH; ++tt) {
    const int t = t0 + tt;
    // wx read issued BEFORE the wait (independent of other blocks)
    f32x4 acc_a, acc_z;
#pragma unroll
    for (int j = 0; j < 4; ++j) {
      const float* wp = wx + ((size_t)(r0 + lg * 4 + j) * TCH + tt) * 1024 + ca;
      acc_a[j] = wp[0];
      acc_z[j] = wp[512];
    }
    if (t > 0) {
      if (tid == 0) {
        while (__hip_atomic_load(cflag + (t - 1), __ATOMIC_RELAXED, __HIP_MEMORY_SCOPE_AGENT) < 8)
          __builtin_amdgcn_s_sleep(1);
      }
      __syncthreads();
      __builtin_amdgcn_fence(__ATOMIC_ACQUIRE, "agent");
      const size_t ap = A0 + (size_t)(t - 1) * 512;
#pragma unroll
      for (int kt = 0; kt < 16; ++kt) {
        bf16x8 af = ldfrag(hs_out + ap + kt * 32);
        acc_a = mfma16(af, ba[kt], acc_a);
        acc_z = mfma16(af, bz[kt], acc_z);
      }
    }
#pragma unroll
    for (int j = 0; j < 4; ++j) {
      float zz = 1.f / (1.f + expf(-acc_z[j]));
      float th = tanhf(acc_a[j]);
      h[j] = zz * h[j] + (1.f - zz) * th;
      hs_out[((size_t)(r0 + lg * 4 + j) * 500 + t) * 512 + ca] = f2bf(h[j]);
    }
    __syncthreads();   // per-wave vmcnt(0) drain before barrier -> stores in L2
    if (tid == 0)
      __hip_atomic_fetch_add(cflag + t, 1, __ATOMIC_RELEASE, __HIP_MEMORY_SCOPE_AGENT);
  }
}

// ---------------- final FC (fp32 compute, bf16 h input) -----------------------
__global__ __launch_bounds__(256) void fc_f32(const u16* __restrict__ hs,
                                              const float* __restrict__ Wfc,
                                              const float* __restrict__ bfc,
                                              float* __restrict__ out) {
  __shared__ float rows[16][1024];
  const int tid = threadIdx.x;
  const int pair0 = blockIdx.x * 16;
  for (int c = tid; c < 2048; c += 256) {
    int p = c >> 7, chunk = c & 127;
    int pr = pair0 + p;
    int b = pr / 500, t = pr - b * 500;
    size_t off;
    if (chunk < 64) off = ((size_t)b * 500 + t) * 512 + (size_t)chunk * 8;
    else            off = ((size_t)(64 + b) * 500 + (499 - t)) * 512 + (size_t)(chunk - 64) * 8;
    u32x4 vh = *(const u32x4*)(hs + off);
    const u16* ph = (const u16*)&vh;
    float* dst = &rows[p][chunk * 8];
#pragma unroll
    for (int e = 0; e < 8; ++e) dst[e] = bf2f(ph[e]);
  }
  __syncthreads();
#pragma unroll
  for (int rep = 0; rep < 3; ++rep) {
    int oi = rep * 256 + tid;
    if (oi < 640) {
      int p = oi / 40, o = oi - p * 40;
      float acc = bfc[o];
#pragma unroll 8
      for (int gg = 0; gg < 1024; ++gg)
        acc = fmaf(rows[p][gg], Wfc[gg * 40 + o], acc);
      out[(size_t)(pair0 + p) * 40 + o] = acc;
    }
  }
}

// ---------------- launch ------------------------------------------------------
extern "C" void kernel_launch(void* const* d_in, const int* in_sizes, int n_in,
                              void* d_out, int out_size, void* d_ws, size_t ws_size,
                              hipStream_t stream) {
  const float* batch = (const float*)d_in[0];
  const float* W0 = (const float*)d_in[2];
  const float* U0 = (const float*)d_in[3];
  const float* W1 = (const float*)d_in[4];
  const float* U1 = (const float*)d_in[5];
  const float* W2 = (const float*)d_in[6];
  const float* U2 = (const float*)d_in[7];
  const float* Wfc = (const float*)d_in[8];
  const float* bfc = (const float*)d_in[9];
  float* out = (float*)d_out;

  char* ws = (char*)d_ws;
  float* wx = (float*)(ws + OFF_WX);
  u16* hsA = (u16*)(ws + OFF_HSA);
  u16* hsB = (u16*)(ws + OFF_HSB);
  u16* xb  = (u16*)(ws + OFF_XB);
  u16* Wt0 = (u16*)(ws + OFF_WT0);
  u16* Wt1 = (u16*)(ws + OFF_WT1);
  u16* Wt2 = (u16*)(ws + OFF_WT2);
  u16* Ut0 = (u16*)(ws + OFF_UT0);
  u16* Ut1 = (u16*)(ws + OFF_UT1);
  u16* Ut2 = (u16*)(ws + OFF_UT2);
  int* cnt = (int*)(ws + OFF_CNT);

  const int cgrid = (int)((N_TOTAL + 255) / 256);
  convert_kernel<<<cgrid, 256, 0, stream>>>(batch, W0, U0, W1, U1, W2, U2,
                                            xb, Wt0, Wt1, Wt2, Ut0, Ut1, Ut2, cnt);

  dim3 ggrid(M_CH / 128, 8);
  // layer 0: reads xb, writes hsA
  for (int c = 0; c < NCH; ++c) {
    wx_gemm_bf16<0><<<ggrid, 256, 0, stream>>>(xb, Wt0, wx, c * TCH);
    ligru_rec<<<64, 256, 0, stream>>>(wx, Ut0, hsA, cnt, c * TCH);
  }
  // layer 1: reads hsA, writes hsB (ping-pong: WAR-safe)
  for (int c = 0; c < NCH; ++c) {
    wx_gemm_bf16<1><<<ggrid, 256, 0, stream>>>(hsA, Wt1, wx, c * TCH);
    ligru_rec<<<64, 256, 0, stream>>>(wx, Ut1, hsB, cnt + 4096, c * TCH);
  }
  // layer 2: reads hsB, writes hsA
  for (int c = 0; c < NCH; ++c) {
    wx_gemm_bf16<1><<<ggrid, 256, 0, stream>>>(hsB, Wt2, wx, c * TCH);
    ligru_rec<<<64, 256, 0, stream>>>(wx, Ut2, hsA, cnt + 8192, c * TCH);
  }
  fc_f32<<<2000, 256, 0, stream>>>(hsA, Wfc, bfc, out);
}